// Round 1
// baseline (209.806 us; speedup 1.0000x reference)
//
#include <hip/hip_runtime.h>
#include <cstdint>

#define BATCH 4096
#define DIN   2560
#define FDIM  2048
#define KP    2592   // 2560 feat cols + 4 bias cols + 28 zero pad = 81*32
#define BM    128
#define BN    128
#define BK    32

typedef unsigned short u16;
typedef __attribute__((ext_vector_type(8))) unsigned short u16x8;
typedef __attribute__((ext_vector_type(8))) __bf16 bf16x8;
typedef __attribute__((ext_vector_type(4))) float f32x4;

__device__ __forceinline__ u16 f2bf(float f) {
  unsigned int u = __float_as_uint(f);
  u += 0x7FFFu + ((u >> 16) & 1u);
  return (u16)(u >> 16);
}

// ---------------------------------------------------------------------------
// Kernel 1: pack [w0|w1|w2|w3|bias_cols|pad] -> bf16 WP [FDIM][KP]
// ---------------------------------------------------------------------------
__global__ __launch_bounds__(256) void pack_w_kernel(
    const float* __restrict__ w0, const float* __restrict__ w1,
    const float* __restrict__ w2, const float* __restrict__ w3,
    const float* __restrict__ b0, const float* __restrict__ b1,
    const float* __restrict__ b2, const float* __restrict__ b3,
    u16* __restrict__ wp)
{
  int idx = blockIdx.x * 256 + threadIdx.x;
  if (idx >= FDIM * KP) return;
  int j = idx / KP;
  int c = idx - j * KP;
  float v;
  if (c < 768)        v = w0[j * 768  + c];
  else if (c < 1792)  v = w1[j * 1024 + (c - 768)];
  else if (c < 2304)  v = w2[j * 512  + (c - 1792)];
  else if (c < 2560)  v = w3[j * 256  + (c - 2304)];
  else if (c < 2564) {
    int e = c - 2560;
    const float* bp = (e == 0) ? b0 : (e == 1) ? b1 : (e == 2) ? b2 : b3;
    v = bp[j];
  } else v = 0.0f;
  wp[idx] = f2bf(v);
}

// ---------------------------------------------------------------------------
// Kernel 2: per-row gating (softmax + top-2 mask) and scaled bf16 features
// FS[b] = [g0*f0[b] | g1*f1[b] | g2*f2[b] | g3*f3[b] | g0..g3 | 0...]
// ---------------------------------------------------------------------------
__global__ __launch_bounds__(256) void gate_scale_kernel(
    const float* __restrict__ f0, const float* __restrict__ f1,
    const float* __restrict__ f2, const float* __restrict__ f3,
    const float* __restrict__ gw, const float* __restrict__ gb,
    u16* __restrict__ fs)
{
  const int b = blockIdx.x;
  const int t = threadIdx.x;

  float fv[10];
  float a0 = 0.f, a1 = 0.f, a2 = 0.f, a3 = 0.f;
#pragma unroll
  for (int i = 0; i < 10; ++i) {
    int c = t + i * 256;
    float v;
    if (c < 768)        v = f0[b * 768  + c];
    else if (c < 1792)  v = f1[b * 1024 + (c - 768)];
    else if (c < 2304)  v = f2[b * 512  + (c - 1792)];
    else                v = f3[b * 256  + (c - 2304)];
    fv[i] = v;
    a0 += v * gw[0 * DIN + c];
    a1 += v * gw[1 * DIN + c];
    a2 += v * gw[2 * DIN + c];
    a3 += v * gw[3 * DIN + c];
  }

  __shared__ float red[4][256];
  red[0][t] = a0; red[1][t] = a1; red[2][t] = a2; red[3][t] = a3;
  __syncthreads();
  for (int s = 128; s > 0; s >>= 1) {
    if (t < s) {
      red[0][t] += red[0][t + s];
      red[1][t] += red[1][t + s];
      red[2][t] += red[2][t + s];
      red[3][t] += red[3][t + s];
    }
    __syncthreads();
  }

  __shared__ float gsel[4];
  if (t == 0) {
    float lg[4];
#pragma unroll
    for (int e = 0; e < 4; ++e) lg[e] = red[e][0] + gb[e];
    float m = fmaxf(fmaxf(lg[0], lg[1]), fmaxf(lg[2], lg[3]));
    float ex[4], s = 0.f;
#pragma unroll
    for (int e = 0; e < 4; ++e) { ex[e] = expf(lg[e] - m); s += ex[e]; }
    // top-2 by logit (softmax monotonic); ties -> lowest index like lax.top_k
    int i1 = 0;
    for (int e = 1; e < 4; ++e) if (lg[e] > lg[i1]) i1 = e;
    int i2 = -1;
    for (int e = 0; e < 4; ++e) {
      if (e == i1) continue;
      if (i2 < 0 || lg[e] > lg[i2]) i2 = e;
    }
    float inv = 1.f / s;
#pragma unroll
    for (int e = 0; e < 4; ++e) gsel[e] = (e == i1 || e == i2) ? ex[e] * inv : 0.f;
  }
  __syncthreads();

  const float g0 = gsel[0], g1 = gsel[1], g2 = gsel[2], g3 = gsel[3];
  u16* row = fs + (size_t)b * KP;
#pragma unroll
  for (int i = 0; i < 10; ++i) {
    int c = t + i * 256;
    float g = (c < 768) ? g0 : (c < 1792) ? g1 : (c < 2304) ? g2 : g3;
    row[c] = f2bf(g * fv[i]);
  }
  if (t < 32) {
    float v = (t < 4) ? gsel[t] : 0.f;  // bias-fold columns
    row[2560 + t] = f2bf(v);
  }
}

// ---------------------------------------------------------------------------
// Kernel 3: C[4096][2048] = FS[4096][KP] @ WP[2048][KP]^T   (bf16 MFMA)
// m97 structure: 128x128 tile, BK=32, 4 waves, global_load_lds width 16.
// ---------------------------------------------------------------------------
__device__ __forceinline__ void gld16(const u16* g, u16* l) {
  __builtin_amdgcn_global_load_lds(
      (const __attribute__((address_space(1))) unsigned int*)(uintptr_t)g,
      (__attribute__((address_space(3))) unsigned int*)(unsigned int)(uintptr_t)l,
      16, 0, 0);
}

__global__ __launch_bounds__(256) void gemm_kernel(
    const u16* __restrict__ A,   // FS [BATCH][KP]
    const u16* __restrict__ B,   // WP [FDIM][KP]
    float* __restrict__ C)       // [BATCH][FDIM]
{
  __shared__ u16 As[BM * BK];    // 8 KB
  __shared__ u16 Bs[BN * BK];    // 8 KB

  const int tid  = threadIdx.x;
  const int wave = tid >> 6;
  const int lane = tid & 63;
  const int bm   = blockIdx.x & 31;   // 32 M-blocks
  const int bn   = blockIdx.x >> 5;   // 16 N-blocks
  const int wm   = (wave >> 1) * 64;  // wave offset in tile (2x2 waves)
  const int wn   = (wave & 1) * 64;
  const int qd   = lane >> 4;
  const int l15  = lane & 15;

  // staging chunk ids: wave w covers chunks [128w,128w+128), lane-contiguous
  const int i0  = tid + 64 * wave;
  const int i1  = i0 + 64;
  const int ar0 = i0 >> 2, ac0 = (i0 & 3) * 8;
  const int ar1 = i1 >> 2, ac1 = (i1 & 3) * 8;

  const u16* Ab = A + (size_t)(bm * BM) * KP;
  const u16* Bb = B + (size_t)(bn * BN) * KP;

  f32x4 acc[4][4] = {};

  for (int k0 = 0; k0 < KP; k0 += BK) {
    gld16(Ab + (size_t)ar0 * KP + k0 + ac0, &As[i0 * 8]);
    gld16(Ab + (size_t)ar1 * KP + k0 + ac1, &As[i1 * 8]);
    gld16(Bb + (size_t)ar0 * KP + k0 + ac0, &Bs[i0 * 8]);
    gld16(Bb + (size_t)ar1 * KP + k0 + ac1, &Bs[i1 * 8]);
    __syncthreads();  // vmcnt(0) drain + barrier: staged tile visible

    bf16x8 af[4], bfr[4];
#pragma unroll
    for (int r = 0; r < 4; ++r)
      af[r] = __builtin_bit_cast(bf16x8,
                *(const u16x8*)&As[(wm + r * 16 + l15) * BK + qd * 8]);
#pragma unroll
    for (int c = 0; c < 4; ++c)
      bfr[c] = __builtin_bit_cast(bf16x8,
                *(const u16x8*)&Bs[(wn + c * 16 + l15) * BK + qd * 8]);
#pragma unroll
    for (int r = 0; r < 4; ++r)
#pragma unroll
      for (int c = 0; c < 4; ++c)
        acc[r][c] = __builtin_amdgcn_mfma_f32_16x16x32_bf16(af[r], bfr[c],
                                                            acc[r][c], 0, 0, 0);
    __syncthreads();  // protect LDS before next stage
  }

  // C/D layout: col = lane&15, row = quad*4 + reg
#pragma unroll
  for (int r = 0; r < 4; ++r) {
#pragma unroll
    for (int c = 0; c < 4; ++c) {
#pragma unroll
      for (int i = 0; i < 4; ++i) {
        int row = bm * BM + wm + r * 16 + qd * 4 + i;
        int col = bn * BN + wn + c * 16 + l15;
        C[(size_t)row * FDIM + col] = acc[r][c][i];
      }
    }
  }
}

// ---------------------------------------------------------------------------
extern "C" void kernel_launch(void* const* d_in, const int* in_sizes, int n_in,
                              void* d_out, int out_size, void* d_ws, size_t ws_size,
                              hipStream_t stream) {
  (void)in_sizes; (void)n_in; (void)out_size; (void)ws_size;
  const float* f0 = (const float*)d_in[0];
  const float* f1 = (const float*)d_in[1];
  const float* f2 = (const float*)d_in[2];
  const float* f3 = (const float*)d_in[3];
  const float* gw = (const float*)d_in[4];
  const float* gb = (const float*)d_in[5];
  const float* w0 = (const float*)d_in[6];
  const float* b0 = (const float*)d_in[7];
  const float* w1 = (const float*)d_in[8];
  const float* b1 = (const float*)d_in[9];
  const float* w2 = (const float*)d_in[10];
  const float* b2 = (const float*)d_in[11];
  const float* w3 = (const float*)d_in[12];
  const float* b3 = (const float*)d_in[13];
  float* out = (float*)d_out;

  u16* fs = (u16*)d_ws;                                     // [BATCH][KP] bf16
  u16* wp = (u16*)((char*)d_ws + (size_t)BATCH * KP * 2);   // [FDIM][KP] bf16

  hipLaunchKernelGGL(pack_w_kernel, dim3((FDIM * KP + 255) / 256), dim3(256), 0,
                     stream, w0, w1, w2, w3, b0, b1, b2, b3, wp);
  hipLaunchKernelGGL(gate_scale_kernel, dim3(BATCH), dim3(256), 0, stream,
                     f0, f1, f2, f3, gw, gb, fs);
  hipLaunchKernelGGL(gemm_kernel, dim3((BATCH / BM) * (FDIM / BN)), dim3(256), 0,
                     stream, fs, wp, out);
}

// Round 2
// 197.033 us; speedup vs baseline: 1.0648x; 1.0648x over previous
//
#include <hip/hip_runtime.h>
#include <cstdint>

#define BATCH 4096
#define DIN   2560
#define FDIM  2048
#define KP    2592   // 2560 feat cols + 4 bias cols + 28 zero pad = 81*32
#define BM    128
#define BN    128
#define BK    32

typedef unsigned short u16;
typedef __attribute__((ext_vector_type(4))) unsigned short u16x4;
typedef __attribute__((ext_vector_type(8))) unsigned short u16x8;
typedef __attribute__((ext_vector_type(8))) __bf16 bf16x8;
typedef __attribute__((ext_vector_type(4))) float f32x4;

__device__ __forceinline__ u16 f2bf(float f) {
  unsigned int u = __float_as_uint(f);
  u += 0x7FFFu + ((u >> 16) & 1u);
  return (u16)(u >> 16);
}

// ---------------------------------------------------------------------------
// Kernel 1: pack [w0|w1|w2|w3|bias_cols|pad] -> bf16 WP [FDIM][KP]
// One thread per 8-u16 (16 B) output chunk; KP/8 = 324 chunks per row.
// Segment boundaries (768,1792,2304,2560) are all multiples of 8.
// ---------------------------------------------------------------------------
__global__ __launch_bounds__(256) void pack_w_kernel(
    const float* __restrict__ w0, const float* __restrict__ w1,
    const float* __restrict__ w2, const float* __restrict__ w3,
    const float* __restrict__ b0, const float* __restrict__ b1,
    const float* __restrict__ b2, const float* __restrict__ b3,
    u16* __restrict__ wp)
{
  int chunk = blockIdx.x * 256 + threadIdx.x;   // [0, 2048*324)
  int j = chunk / 324;
  int s = chunk - j * 324;
  u16x8 o;
  if (s < 320) {
    const float* src; int col;
    if (s < 96)       { src = w0 + j * 768;  col = s * 8; }
    else if (s < 224) { src = w1 + j * 1024; col = (s - 96) * 8; }
    else if (s < 288) { src = w2 + j * 512;  col = (s - 224) * 8; }
    else              { src = w3 + j * 256;  col = (s - 288) * 8; }
    float4 v0 = *(const float4*)(src + col);
    float4 v1 = *(const float4*)(src + col + 4);
    o[0] = f2bf(v0.x); o[1] = f2bf(v0.y); o[2] = f2bf(v0.z); o[3] = f2bf(v0.w);
    o[4] = f2bf(v1.x); o[5] = f2bf(v1.y); o[6] = f2bf(v1.z); o[7] = f2bf(v1.w);
  } else if (s == 320) {
    o[0] = f2bf(b0[j]); o[1] = f2bf(b1[j]); o[2] = f2bf(b2[j]); o[3] = f2bf(b3[j]);
    o[4] = 0; o[5] = 0; o[6] = 0; o[7] = 0;
  } else {
    o = (u16x8)(u16)0;
  }
  *(u16x8*)(wp + (size_t)j * KP + s * 8) = o;
}

// ---------------------------------------------------------------------------
// Kernel 2: one WAVE per row. float4 loads, 64-lane shuffle reduce for the 4
// gate logits, all-lane redundant softmax/top-2, scaled bf16 stores.
// FS[b] = [g0*f0[b] | g1*f1[b] | g2*f2[b] | g3*f3[b] | g0..g3 | 0...]
// ---------------------------------------------------------------------------
__global__ __launch_bounds__(256) void gate_scale_kernel(
    const float* __restrict__ f0, const float* __restrict__ f1,
    const float* __restrict__ f2, const float* __restrict__ f3,
    const float* __restrict__ gw, const float* __restrict__ gb,
    u16* __restrict__ fs)
{
  const int wave = threadIdx.x >> 6;
  const int lane = threadIdx.x & 63;
  const int b    = blockIdx.x * 4 + wave;

  // 2560 floats = 640 float4 per row; 10 float4 per lane. Segment boundaries
  // (192,448,576 in float4 units) are multiples of 64 -> wave-uniform branches.
  float4 fv[10];
  float a[4] = {0.f, 0.f, 0.f, 0.f};
#pragma unroll
  for (int i = 0; i < 10; ++i) {
    int c4 = lane + i * 64;
    const float4* fp;
    if (c4 < 192)      fp = (const float4*)f0 + b * 192 + c4;
    else if (c4 < 448) fp = (const float4*)f1 + b * 256 + (c4 - 192);
    else if (c4 < 576) fp = (const float4*)f2 + b * 128 + (c4 - 448);
    else               fp = (const float4*)f3 + b * 64  + (c4 - 576);
    float4 v = *fp;
    fv[i] = v;
#pragma unroll
    for (int e = 0; e < 4; ++e) {
      float4 g = *((const float4*)(gw + e * DIN) + c4);
      a[e] += v.x * g.x + v.y * g.y + v.z * g.z + v.w * g.w;
    }
  }
#pragma unroll
  for (int e = 0; e < 4; ++e) {
#pragma unroll
    for (int m = 32; m >= 1; m >>= 1) a[e] += __shfl_xor(a[e], m, 64);
    a[e] += gb[e];
  }

  // softmax + top-2 by logit (monotonic); ties -> lowest index like lax.top_k
  float mx = fmaxf(fmaxf(a[0], a[1]), fmaxf(a[2], a[3]));
  float ex[4], ssum = 0.f;
#pragma unroll
  for (int e = 0; e < 4; ++e) { ex[e] = __expf(a[e] - mx); ssum += ex[e]; }
  int i1 = 0;
#pragma unroll
  for (int e = 1; e < 4; ++e) if (a[e] > a[i1]) i1 = e;
  int i2 = -1;
#pragma unroll
  for (int e = 0; e < 4; ++e) {
    if (e == i1) continue;
    if (i2 < 0 || a[e] > a[i2]) i2 = e;
  }
  float inv = 1.f / ssum;
  float g[4];
#pragma unroll
  for (int e = 0; e < 4; ++e) g[e] = (e == i1 || e == i2) ? ex[e] * inv : 0.f;

  u16* row = fs + (size_t)b * KP;
#pragma unroll
  for (int i = 0; i < 10; ++i) {
    int c4 = lane + i * 64;
    float gg = (c4 < 192) ? g[0] : (c4 < 448) ? g[1] : (c4 < 576) ? g[2] : g[3];
    u16x4 o = { f2bf(fv[i].x * gg), f2bf(fv[i].y * gg),
                f2bf(fv[i].z * gg), f2bf(fv[i].w * gg) };
    *(u16x4*)(row + c4 * 4) = o;
  }
  if (lane < 32) row[2560 + lane] = (lane < 4) ? f2bf(g[lane]) : (u16)0;
}

// ---------------------------------------------------------------------------
// Kernel 3: C[4096][2048] = FS[4096][KP] @ WP[2048][KP]^T   (bf16 MFMA)
// 128x128 tile, BK=32, 4 waves, global_load_lds width 16.
// XOR swizzle: LDS[row][slot] holds global chunk slot^((row>>1)&3) so that
// ds_read_b128 fragment reads hit each quad-bank-group exactly 2x (free).
// ---------------------------------------------------------------------------
__device__ __forceinline__ void gld16(const u16* g, u16* l) {
  __builtin_amdgcn_global_load_lds(
      (const __attribute__((address_space(1))) unsigned int*)(uintptr_t)g,
      (__attribute__((address_space(3))) unsigned int*)(unsigned int)(uintptr_t)l,
      16, 0, 0);
}

__global__ __launch_bounds__(256) void gemm_kernel(
    const u16* __restrict__ A,   // FS [BATCH][KP]
    const u16* __restrict__ B,   // WP [FDIM][KP]
    float* __restrict__ C)       // [BATCH][FDIM]
{
  __shared__ u16 As[BM * BK];    // 8 KB
  __shared__ u16 Bs[BN * BK];    // 8 KB

  const int tid  = threadIdx.x;
  const int wave = tid >> 6;
  const int lane = tid & 63;
  const int bm   = blockIdx.x & 31;   // 32 M-blocks
  const int bn   = blockIdx.x >> 5;   // 16 N-blocks
  const int wm   = (wave >> 1) * 64;  // wave offset in tile (2x2 waves)
  const int wn   = (wave & 1) * 64;
  const int qd   = lane >> 4;
  const int l15  = lane & 15;
  // swizzled chunk slot for fragment reads (wm/wn/r*16 are multiples of 16,
  // so (row>>1)&3 == (l15>>1)&3)
  const int sw   = (qd ^ ((l15 >> 1) & 3)) * 8;

  // staging chunk ids: 4 chunks of 8 u16 per row; LDS slot forced contiguous
  // by global_load_lds, so the swizzle is applied to the global source chunk.
  const int i0  = tid + 64 * wave;
  const int i1  = i0 + 64;
  const int ar0 = i0 >> 2, ac0 = (((i0 & 3) ^ ((ar0 >> 1) & 3))) * 8;
  const int ar1 = i1 >> 2, ac1 = (((i1 & 3) ^ ((ar1 >> 1) & 3))) * 8;

  const u16* Ab = A + (size_t)(bm * BM) * KP;
  const u16* Bb = B + (size_t)(bn * BN) * KP;

  f32x4 acc[4][4] = {};

  for (int k0 = 0; k0 < KP; k0 += BK) {
    gld16(Ab + (size_t)ar0 * KP + k0 + ac0, &As[i0 * 8]);
    gld16(Ab + (size_t)ar1 * KP + k0 + ac1, &As[i1 * 8]);
    gld16(Bb + (size_t)ar0 * KP + k0 + ac0, &Bs[i0 * 8]);
    gld16(Bb + (size_t)ar1 * KP + k0 + ac1, &Bs[i1 * 8]);
    __syncthreads();  // vmcnt(0) drain + barrier: staged tile visible

    bf16x8 af[4], bfr[4];
#pragma unroll
    for (int r = 0; r < 4; ++r)
      af[r] = __builtin_bit_cast(bf16x8,
                *(const u16x8*)&As[(wm + r * 16 + l15) * BK + sw]);
#pragma unroll
    for (int c = 0; c < 4; ++c)
      bfr[c] = __builtin_bit_cast(bf16x8,
                *(const u16x8*)&Bs[(wn + c * 16 + l15) * BK + sw]);
#pragma unroll
    for (int r = 0; r < 4; ++r)
#pragma unroll
      for (int c = 0; c < 4; ++c)
        acc[r][c] = __builtin_amdgcn_mfma_f32_16x16x32_bf16(af[r], bfr[c],
                                                            acc[r][c], 0, 0, 0);
    __syncthreads();  // protect LDS before next stage
  }

  // C/D layout: col = lane&15, row = quad*4 + reg
#pragma unroll
  for (int r = 0; r < 4; ++r) {
#pragma unroll
    for (int c = 0; c < 4; ++c) {
#pragma unroll
      for (int i = 0; i < 4; ++i) {
        int row = bm * BM + wm + r * 16 + qd * 4 + i;
        int col = bn * BN + wn + c * 16 + l15;
        C[(size_t)row * FDIM + col] = acc[r][c][i];
      }
    }
  }
}

// ---------------------------------------------------------------------------
extern "C" void kernel_launch(void* const* d_in, const int* in_sizes, int n_in,
                              void* d_out, int out_size, void* d_ws, size_t ws_size,
                              hipStream_t stream) {
  (void)in_sizes; (void)n_in; (void)out_size; (void)ws_size;
  const float* f0 = (const float*)d_in[0];
  const float* f1 = (const float*)d_in[1];
  const float* f2 = (const float*)d_in[2];
  const float* f3 = (const float*)d_in[3];
  const float* gw = (const float*)d_in[4];
  const float* gb = (const float*)d_in[5];
  const float* w0 = (const float*)d_in[6];
  const float* b0 = (const float*)d_in[7];
  const float* w1 = (const float*)d_in[8];
  const float* b1 = (const float*)d_in[9];
  const float* w2 = (const float*)d_in[10];
  const float* b2 = (const float*)d_in[11];
  const float* w3 = (const float*)d_in[12];
  const float* b3 = (const float*)d_in[13];
  float* out = (float*)d_out;

  u16* fs = (u16*)d_ws;                                     // [BATCH][KP] bf16
  u16* wp = (u16*)((char*)d_ws + (size_t)BATCH * KP * 2);   // [FDIM][KP] bf16

  hipLaunchKernelGGL(pack_w_kernel, dim3((FDIM * (KP / 8) + 255) / 256), dim3(256),
                     0, stream, w0, w1, w2, w3, b0, b1, b2, b3, wp);
  hipLaunchKernelGGL(gate_scale_kernel, dim3(BATCH / 4), dim3(256), 0, stream,
                     f0, f1, f2, f3, gw, gb, fs);
  hipLaunchKernelGGL(gemm_kernel, dim3((BATCH / BM) * (FDIM / BN)), dim3(256), 0,
                     stream, fs, wp, out);
}

// Round 3
// 188.553 us; speedup vs baseline: 1.1127x; 1.0450x over previous
//
#include <hip/hip_runtime.h>
#include <cstdint>

#define BATCH 4096
#define DIN   2560
#define FDIM  2048
#define KP    2592   // 2560 feat cols + 4 bias cols + 28 zero pad = 81*32
#define BM    128
#define BN    128
#define BK    32

typedef unsigned short u16;
typedef __attribute__((ext_vector_type(4))) unsigned short u16x4;
typedef __attribute__((ext_vector_type(8))) unsigned short u16x8;
typedef __attribute__((ext_vector_type(8))) __bf16 bf16x8;
typedef __attribute__((ext_vector_type(4))) float f32x4;

__device__ __forceinline__ u16 f2bf(float f) {
  unsigned int u = __float_as_uint(f);
  u += 0x7FFFu + ((u >> 16) & 1u);
  return (u16)(u >> 16);
}

// ---------------------------------------------------------------------------
// Kernel 1 (merged prep): blocks [0, 2592): pack W -> bf16 WP [FDIM][KP]
//                         blocks [2592, 3616): gate+scale -> bf16 FS [BATCH][KP]
// ---------------------------------------------------------------------------
#define PACK_BLOCKS 2592   // FDIM * (KP/8) / 256
#define GATE_BLOCKS 1024   // BATCH / 4

__global__ __launch_bounds__(256) void prep_kernel(
    const float* __restrict__ f0, const float* __restrict__ f1,
    const float* __restrict__ f2, const float* __restrict__ f3,
    const float* __restrict__ gw, const float* __restrict__ gb,
    const float* __restrict__ w0, const float* __restrict__ w1,
    const float* __restrict__ w2, const float* __restrict__ w3,
    const float* __restrict__ b0, const float* __restrict__ b1,
    const float* __restrict__ b2, const float* __restrict__ b3,
    u16* __restrict__ wp, u16* __restrict__ fs)
{
  if (blockIdx.x < PACK_BLOCKS) {
    // ---- pack W: one thread per 8-u16 (16 B) chunk; KP/8 = 324 chunks/row.
    int chunk = blockIdx.x * 256 + threadIdx.x;   // [0, 2048*324)
    int j = chunk / 324;
    int s = chunk - j * 324;
    u16x8 o;
    if (s < 320) {
      const float* src; int col;
      if (s < 96)       { src = w0 + j * 768;  col = s * 8; }
      else if (s < 224) { src = w1 + j * 1024; col = (s - 96) * 8; }
      else if (s < 288) { src = w2 + j * 512;  col = (s - 224) * 8; }
      else              { src = w3 + j * 256;  col = (s - 288) * 8; }
      float4 v0 = *(const float4*)(src + col);
      float4 v1 = *(const float4*)(src + col + 4);
      o[0] = f2bf(v0.x); o[1] = f2bf(v0.y); o[2] = f2bf(v0.z); o[3] = f2bf(v0.w);
      o[4] = f2bf(v1.x); o[5] = f2bf(v1.y); o[6] = f2bf(v1.z); o[7] = f2bf(v1.w);
    } else if (s == 320) {
      o[0] = f2bf(b0[j]); o[1] = f2bf(b1[j]); o[2] = f2bf(b2[j]); o[3] = f2bf(b3[j]);
      o[4] = 0; o[5] = 0; o[6] = 0; o[7] = 0;
    } else {
      o = (u16x8)(u16)0;
    }
    *(u16x8*)(wp + (size_t)j * KP + s * 8) = o;
    return;
  }

  // ---- gate+scale: one WAVE per row.
  const int wave = threadIdx.x >> 6;
  const int lane = threadIdx.x & 63;
  const int b    = (blockIdx.x - PACK_BLOCKS) * 4 + wave;

  // 640 float4 per row; 10 per lane. Segment boundaries (192,448,576 in
  // float4 units) are multiples of 64 -> wave-uniform branches.
  float4 fv[10];
  float a[4] = {0.f, 0.f, 0.f, 0.f};
#pragma unroll
  for (int i = 0; i < 10; ++i) {
    int c4 = lane + i * 64;
    const float4* fp;
    if (c4 < 192)      fp = (const float4*)f0 + b * 192 + c4;
    else if (c4 < 448) fp = (const float4*)f1 + b * 256 + (c4 - 192);
    else if (c4 < 576) fp = (const float4*)f2 + b * 128 + (c4 - 448);
    else               fp = (const float4*)f3 + b * 64  + (c4 - 576);
    float4 v = *fp;
    fv[i] = v;
#pragma unroll
    for (int e = 0; e < 4; ++e) {
      float4 g = *((const float4*)(gw + e * DIN) + c4);
      a[e] += v.x * g.x + v.y * g.y + v.z * g.z + v.w * g.w;
    }
  }
#pragma unroll
  for (int e = 0; e < 4; ++e) {
#pragma unroll
    for (int m = 32; m >= 1; m >>= 1) a[e] += __shfl_xor(a[e], m, 64);
    a[e] += gb[e];
  }

  // softmax + top-2 by logit (monotonic); ties -> lowest index like lax.top_k
  float mx = fmaxf(fmaxf(a[0], a[1]), fmaxf(a[2], a[3]));
  float ex[4], ssum = 0.f;
#pragma unroll
  for (int e = 0; e < 4; ++e) { ex[e] = __expf(a[e] - mx); ssum += ex[e]; }
  int i1 = 0;
#pragma unroll
  for (int e = 1; e < 4; ++e) if (a[e] > a[i1]) i1 = e;
  int i2 = -1;
#pragma unroll
  for (int e = 0; e < 4; ++e) {
    if (e == i1) continue;
    if (i2 < 0 || a[e] > a[i2]) i2 = e;
  }
  float inv = 1.f / ssum;
  float g[4];
#pragma unroll
  for (int e = 0; e < 4; ++e) g[e] = (e == i1 || e == i2) ? ex[e] * inv : 0.f;

  u16* row = fs + (size_t)b * KP;
#pragma unroll
  for (int i = 0; i < 10; ++i) {
    int c4 = lane + i * 64;
    float gg = (c4 < 192) ? g[0] : (c4 < 448) ? g[1] : (c4 < 576) ? g[2] : g[3];
    u16x4 o = { f2bf(fv[i].x * gg), f2bf(fv[i].y * gg),
                f2bf(fv[i].z * gg), f2bf(fv[i].w * gg) };
    *(u16x4*)(row + c4 * 4) = o;
  }
  if (lane < 32) row[2560 + lane] = (lane < 4) ? f2bf(g[lane]) : (u16)0;
}

// ---------------------------------------------------------------------------
// Kernel 2: C[4096][2048] = FS[4096][KP] @ WP[2048][KP]^T   (bf16 MFMA)
// 128x128 tile, BK=32, 8 waves (512 thr) for 16 waves/CU at grid=2 blocks/CU.
// Wave grid 2x4: each wave 64 rows x 32 cols (acc 4x2). XOR swizzle keeps
// ds_read_b128 fragment reads conflict-free (verified 0 conflicts in R2).
// ---------------------------------------------------------------------------
__device__ __forceinline__ void gld16(const u16* g, u16* l) {
  __builtin_amdgcn_global_load_lds(
      (const __attribute__((address_space(1))) unsigned int*)(uintptr_t)g,
      (__attribute__((address_space(3))) unsigned int*)(unsigned int)(uintptr_t)l,
      16, 0, 0);
}

__global__ __launch_bounds__(512, 4) void gemm_kernel(
    const u16* __restrict__ A,   // FS [BATCH][KP]
    const u16* __restrict__ B,   // WP [FDIM][KP]
    float* __restrict__ C)       // [BATCH][FDIM]
{
  __shared__ u16 As[BM * BK];    // 8 KB
  __shared__ u16 Bs[BN * BK];    // 8 KB

  const int tid  = threadIdx.x;
  const int wave = tid >> 6;
  const int lane = tid & 63;
  const int bm   = blockIdx.x & 31;   // 32 M-blocks
  const int bn   = blockIdx.x >> 5;   // 16 N-blocks
  const int wm   = (wave >> 2) * 64;  // 2x4 wave grid
  const int wn   = (wave & 3) * 32;
  const int qd   = lane >> 4;
  const int l15  = lane & 15;
  // swizzled chunk slot for fragment reads (row offsets are multiples of 16,
  // so (row>>1)&3 == (l15>>1)&3)
  const int sw   = (qd ^ ((l15 >> 1) & 3)) * 8;

  // staging: A tile = 512 chunks of 16 B, B tile = 512 chunks; 1 of each per
  // thread. LDS slot is forced lane-contiguous by global_load_lds, so the XOR
  // swizzle is applied to the global source chunk.
  const int ar = tid >> 2;
  const int ac = ((tid & 3) ^ ((ar >> 1) & 3)) * 8;

  const u16* Ab = A + (size_t)(bm * BM) * KP;
  const u16* Bb = B + (size_t)(bn * BN) * KP;

  f32x4 acc[4][2] = {};

  for (int k0 = 0; k0 < KP; k0 += BK) {
    gld16(Ab + (size_t)ar * KP + k0 + ac, &As[tid * 8]);
    gld16(Bb + (size_t)ar * KP + k0 + ac, &Bs[tid * 8]);
    __syncthreads();  // vmcnt(0) drain + barrier: staged tile visible

    bf16x8 af[4], bfr[2];
#pragma unroll
    for (int r = 0; r < 4; ++r)
      af[r] = __builtin_bit_cast(bf16x8,
                *(const u16x8*)&As[(wm + r * 16 + l15) * BK + sw]);
#pragma unroll
    for (int c = 0; c < 2; ++c)
      bfr[c] = __builtin_bit_cast(bf16x8,
                *(const u16x8*)&Bs[(wn + c * 16 + l15) * BK + sw]);
#pragma unroll
    for (int r = 0; r < 4; ++r)
#pragma unroll
      for (int c = 0; c < 2; ++c)
        acc[r][c] = __builtin_amdgcn_mfma_f32_16x16x32_bf16(af[r], bfr[c],
                                                            acc[r][c], 0, 0, 0);
    __syncthreads();  // protect LDS before next stage
  }

  // C/D layout: col = lane&15, row = quad*4 + reg
#pragma unroll
  for (int r = 0; r < 4; ++r) {
#pragma unroll
    for (int c = 0; c < 2; ++c) {
#pragma unroll
      for (int i = 0; i < 4; ++i) {
        int row = bm * BM + wm + r * 16 + qd * 4 + i;
        int col = bn * BN + wn + c * 16 + l15;
        C[(size_t)row * FDIM + col] = acc[r][c][i];
      }
    }
  }
}

// ---------------------------------------------------------------------------
extern "C" void kernel_launch(void* const* d_in, const int* in_sizes, int n_in,
                              void* d_out, int out_size, void* d_ws, size_t ws_size,
                              hipStream_t stream) {
  (void)in_sizes; (void)n_in; (void)out_size; (void)ws_size;
  const float* f0 = (const float*)d_in[0];
  const float* f1 = (const float*)d_in[1];
  const float* f2 = (const float*)d_in[2];
  const float* f3 = (const float*)d_in[3];
  const float* gw = (const float*)d_in[4];
  const float* gb = (const float*)d_in[5];
  const float* w0 = (const float*)d_in[6];
  const float* b0 = (const float*)d_in[7];
  const float* w1 = (const float*)d_in[8];
  const float* b1 = (const float*)d_in[9];
  const float* w2 = (const float*)d_in[10];
  const float* b2 = (const float*)d_in[11];
  const float* w3 = (const float*)d_in[12];
  const float* b3 = (const float*)d_in[13];
  float* out = (float*)d_out;

  u16* fs = (u16*)d_ws;                                     // [BATCH][KP] bf16
  u16* wp = (u16*)((char*)d_ws + (size_t)BATCH * KP * 2);   // [FDIM][KP] bf16

  hipLaunchKernelGGL(prep_kernel, dim3(PACK_BLOCKS + GATE_BLOCKS), dim3(256), 0,
                     stream, f0, f1, f2, f3, gw, gb,
                     w0, w1, w2, w3, b0, b1, b2, b3, wp, fs);
  hipLaunchKernelGGL(gemm_kernel, dim3((BATCH / BM) * (FDIM / BN)), dim3(512), 0,
                     stream, fs, wp, out);
}